// Round 1
// baseline (2030.405 us; speedup 1.0000x reference)
//
#include <hip/hip_runtime.h>

typedef unsigned short u16;
typedef __attribute__((ext_vector_type(8))) short short8;
typedef __attribute__((ext_vector_type(4))) float f32x4;

#define N_NODES 40000
#define N_EDGES 640000

// ---------- bf16 helpers (RNE, matches v_cvt_pk_bf16_f32) ----------
__device__ __forceinline__ u16 f2bf(float f) {
  unsigned int u = __builtin_bit_cast(unsigned int, f);
  u += 0x7FFFu + ((u >> 16) & 1u);
  return (u16)(u >> 16);
}
__device__ __forceinline__ float bf2f(u16 h) {
  unsigned int u = ((unsigned int)h) << 16;
  return __builtin_bit_cast(float, u);
}

// ---------- prep: W1/W2 f32 -> bf16, permuted into MFMA B-fragment order ----
// B frag for (ntile,ks): lane l holds B[k=ks*32+(l>>4)*8+i][n=ntile*16+(l&15)]
// stored as [layer][ntile][ks][lane][8] contiguous -> frag load = 1KB coalesced
__global__ void prep_weights(const float* __restrict__ W1,
                             const float* __restrict__ W2,
                             u16* __restrict__ w1t, u16* __restrict__ w2t) {
  int gid = blockIdx.x * 256 + threadIdx.x;
  if (gid < 3 * 16 * 8 * 64) {            // W1: 3 layers x 16 ntiles x 8 ks x 64 lanes
    int l = gid >> 13;
    int rem = gid & 8191;
    int ntg = rem >> 9;
    int ks = (rem >> 6) & 7;
    int lane = rem & 63;
    int n = ntg * 16 + (lane & 15);
    int k0 = ks * 32 + (lane >> 4) * 8;
    const float* s = W1 + l * 65536 + n * 256 + k0;
    u16* d = w1t + (size_t)gid * 8;
#pragma unroll
    for (int j = 0; j < 8; ++j) d[j] = f2bf(s[j]);
  } else if (gid < 3 * 16 * 8 * 64 + 3 * 8 * 8 * 64) {  // W2: 8 ntiles
    int g = gid - 3 * 16 * 8 * 64;
    int l = g >> 12;
    int rem = g & 4095;
    int ntg = rem >> 9;
    int ks = (rem >> 6) & 7;
    int lane = rem & 63;
    int n = ntg * 16 + (lane & 15);
    int k0 = ks * 32 + (lane >> 4) * 8;
    const float* s = W2 + l * 32768 + n * 256 + k0;
    u16* d = w2t + (size_t)g * 8;
#pragma unroll
    for (int j = 0; j < 8; ++j) d[j] = f2bf(s[j]);
  }
}

// ---------- GEMM1: x[64e][256] = concat(h[src],e) @ W1^T ; + f32 col stats --
__global__ __launch_bounds__(256) void gin_gemm1(
    const float* __restrict__ hin, const float* __restrict__ ef,
    const int* __restrict__ src, const u16* __restrict__ w1t,
    u16* __restrict__ xout, float* __restrict__ stats, int relu_in) {
  __shared__ u16 sA[64][264];  // +8 pad: stride 528B -> 2-way (free) on frag reads
  const int tid = threadIdx.x;
  const long e0 = (long)blockIdx.x * 64;

  // ---- stage A tile: gather h[src] (cols 0..127) + e (cols 128..255), cvt bf16
  {
    const int c = tid & 31;            // 16B chunk within row (32 chunks)
    const int kb = (c & 15) * 8;       // f32 col offset within the half
    for (int it = 0; it < 8; ++it) {
      const int r = it * 8 + (tid >> 5);
      const long row = e0 + r;
      const float* p;
      if (c < 16) {
        const int s = src[row];
        p = hin + (long)s * 128 + kb;
      } else {
        p = ef + row * 128 + kb;
      }
      const float4* p4 = reinterpret_cast<const float4*>(p);
      float4 f0 = p4[0], f1 = p4[1];
      if (relu_in) {
        f0.x = fmaxf(f0.x, 0.f); f0.y = fmaxf(f0.y, 0.f);
        f0.z = fmaxf(f0.z, 0.f); f0.w = fmaxf(f0.w, 0.f);
        f1.x = fmaxf(f1.x, 0.f); f1.y = fmaxf(f1.y, 0.f);
        f1.z = fmaxf(f1.z, 0.f); f1.w = fmaxf(f1.w, 0.f);
      }
      short8 v;
      v[0] = (short)f2bf(f0.x); v[1] = (short)f2bf(f0.y);
      v[2] = (short)f2bf(f0.z); v[3] = (short)f2bf(f0.w);
      v[4] = (short)f2bf(f1.x); v[5] = (short)f2bf(f1.y);
      v[6] = (short)f2bf(f1.z); v[7] = (short)f2bf(f1.w);
      *(short8*)&sA[r][c * 8] = v;
    }
  }
  __syncthreads();

  const int wid = tid >> 6, lane = tid & 63;
  const int lrow = lane & 15, lk = lane >> 4;
  f32x4 acc[4][4] = {};
  const u16* wbase = w1t + (size_t)wid * 16384;  // this wave's 4 ntiles
  for (int ks = 0; ks < 8; ++ks) {
    short8 af[4];
#pragma unroll
    for (int mt = 0; mt < 4; ++mt)
      af[mt] = *(const short8*)&sA[mt * 16 + lrow][ks * 32 + lk * 8];
#pragma unroll
    for (int nt = 0; nt < 4; ++nt) {
      short8 bf = *(const short8*)(wbase + ((nt * 8 + ks) * 64 + lane) * 8);
#pragma unroll
      for (int mt = 0; mt < 4; ++mt)
        acc[mt][nt] =
            __builtin_amdgcn_mfma_f32_16x16x32_bf16(af[mt], bf, acc[mt][nt], 0, 0, 0);
    }
  }

  // ---- epilogue: write x (bf16) + per-column sum / sumsq partials
  float* statp = stats + (blockIdx.x & 63) * 512;
#pragma unroll
  for (int nt = 0; nt < 4; ++nt) {
    const int col = wid * 64 + nt * 16 + lrow;
    float sm = 0.f, sq = 0.f;
#pragma unroll
    for (int mt = 0; mt < 4; ++mt) {
#pragma unroll
      for (int i = 0; i < 4; ++i) {
        float v = acc[mt][nt][i];
        const long row = e0 + mt * 16 + lk * 4 + i;
        xout[(size_t)row * 256 + col] = f2bf(v);
        sm += v; sq += v * v;
      }
    }
    sm += __shfl_xor(sm, 16); sq += __shfl_xor(sq, 16);
    sm += __shfl_xor(sm, 32); sq += __shfl_xor(sq, 32);
    if (lk == 0) {
      atomicAdd(statp + col, sm);
      atomicAdd(statp + 256 + col, sq);
    }
  }
}

// ---------- BN finalize: a = gamma*rsqrt(var+eps), b = beta - mu*a ----------
__global__ void gin_bnstats(const float* __restrict__ stats,
                            const float* __restrict__ gamma,
                            const float* __restrict__ beta,
                            float* __restrict__ ab) {
  int c = threadIdx.x;  // 256 threads
  float sm = 0.f, sq = 0.f;
  for (int i = 0; i < 64; ++i) {
    sm += stats[i * 512 + c];
    sq += stats[i * 512 + 256 + c];
  }
  const float inv = 1.0f / (float)N_EDGES;
  float mu = sm * inv;
  float var = fmaxf(sq * inv - mu * mu, 0.f);
  float a = gamma[c] * rsqrtf(var + 1e-5f);
  ab[c] = a;
  ab[256 + c] = beta[c] - mu * a;
}

// ---------- GEMM2: m = relu(x*a+b) @ W2^T ; scatter-add to hnext[dst] -------
__global__ __launch_bounds__(256) void gin_gemm2(
    const u16* __restrict__ xin, const u16* __restrict__ w2t,
    const float* __restrict__ ab, const float* __restrict__ b2,
    const int* __restrict__ dst, float* __restrict__ hnext) {
  __shared__ u16 sX[64][264];
  const int tid = threadIdx.x;
  const long e0 = (long)blockIdx.x * 64;

  // ---- stage normalized+relu'd x tile (bf16)
  {
    const int c = tid & 31;
    const int kb = c * 8;
    float a_[8], s_[8];
#pragma unroll
    for (int j = 0; j < 8; ++j) { a_[j] = ab[kb + j]; s_[j] = ab[256 + kb + j]; }
    for (int it = 0; it < 8; ++it) {
      const int r = it * 8 + (tid >> 5);
      short8 u = *(const short8*)(xin + (size_t)(e0 + r) * 256 + kb);
      short8 v;
#pragma unroll
      for (int j = 0; j < 8; ++j) {
        float f = bf2f((u16)u[j]);
        f = fmaxf(f * a_[j] + s_[j], 0.f);
        v[j] = (short)f2bf(f);
      }
      *(short8*)&sX[r][kb] = v;
    }
  }
  __syncthreads();

  const int wid = tid >> 6, lane = tid & 63;
  const int lrow = lane & 15, lk = lane >> 4;
  f32x4 acc[4][2] = {};
  const u16* wbase = w2t + (size_t)wid * 8192;  // this wave's 2 ntiles
  for (int ks = 0; ks < 8; ++ks) {
    short8 af[4];
#pragma unroll
    for (int mt = 0; mt < 4; ++mt)
      af[mt] = *(const short8*)&sX[mt * 16 + lrow][ks * 32 + lk * 8];
#pragma unroll
    for (int nt = 0; nt < 2; ++nt) {
      short8 bf = *(const short8*)(wbase + ((nt * 8 + ks) * 64 + lane) * 8);
#pragma unroll
      for (int mt = 0; mt < 4; ++mt)
        acc[mt][nt] =
            __builtin_amdgcn_mfma_f32_16x16x32_bf16(af[mt], bf, acc[mt][nt], 0, 0, 0);
    }
  }

  // ---- epilogue: scatter-add messages to dst nodes (+ b2)
  float bb[2];
#pragma unroll
  for (int nt = 0; nt < 2; ++nt) bb[nt] = b2[wid * 32 + nt * 16 + lrow];
#pragma unroll
  for (int mt = 0; mt < 4; ++mt) {
    int nd[4];
#pragma unroll
    for (int i = 0; i < 4; ++i) nd[i] = dst[e0 + mt * 16 + lk * 4 + i];
#pragma unroll
    for (int nt = 0; nt < 2; ++nt) {
      const int col = wid * 32 + nt * 16 + lrow;
#pragma unroll
      for (int i = 0; i < 4; ++i)
        atomicAdd(hnext + (size_t)nd[i] * 128 + col, acc[mt][nt][i] + bb[nt]);
    }
  }
}

// ---------- launch ----------
extern "C" void kernel_launch(void* const* d_in, const int* in_sizes, int n_in,
                              void* d_out, int out_size, void* d_ws, size_t ws_size,
                              hipStream_t stream) {
  const float* h     = (const float*)d_in[0];
  const float* e     = (const float*)d_in[1];
  const float* W1    = (const float*)d_in[2];
  // d_in[3] = b1: cancels exactly in BatchNorm -> unused
  const float* gamma = (const float*)d_in[4];
  const float* beta  = (const float*)d_in[5];
  const float* W2    = (const float*)d_in[6];
  const float* b2    = (const float*)d_in[7];
  const int* src     = (const int*)d_in[8];
  const int* dst     = (const int*)d_in[9];
  float* out = (float*)d_out;

  char* ws = (char*)d_ws;
  u16*   xbuf  = (u16*)(ws);                      // 640000*256*2 = 327,680,000
  float* h1    = (float*)(ws + 327680000);        // 20,480,000
  float* h2    = (float*)(ws + 348160000);        // 20,480,000
  u16*   w1t   = (u16*)(ws + 368640000);          // 393,216
  u16*   w2t   = (u16*)(ws + 369033216);          // 196,608
  float* stats = (float*)(ws + 369229824);        // 64*512*4 = 131,072
  float* ab    = (float*)(ws + 369360896);        // 2,048

  prep_weights<<<144, 256, 0, stream>>>(W1, W2, w1t, w2t);

  const float* hin = h;
  const int nblk = N_EDGES / 64;  // 10000
  for (int l = 0; l < 3; ++l) {
    hipMemsetAsync(stats, 0, 64 * 512 * 4, stream);
    gin_gemm1<<<nblk, 256, 0, stream>>>(hin, e, src, w1t + (size_t)l * 65536,
                                        xbuf, stats, l > 0 ? 1 : 0);
    gin_bnstats<<<1, 256, 0, stream>>>(stats, gamma + l * 256, beta + l * 256, ab);
    float* hnext = (l == 0) ? h1 : (l == 1) ? h2 : out;
    hipMemsetAsync(hnext, 0, (size_t)N_NODES * 128 * 4, stream);
    gin_gemm2<<<nblk, 256, 0, stream>>>(xbuf, w2t + (size_t)l * 32768, ab,
                                        b2 + l * 128, dst, hnext);
    hin = hnext;
  }
}